// Round 4
// baseline (1205.254 us; speedup 1.0000x reference)
//
#include <hip/hip_runtime.h>
#include <hip/hip_bf16.h>

typedef __attribute__((ext_vector_type(8))) short short8;
typedef __attribute__((ext_vector_type(4))) short short4v;
typedef __attribute__((ext_vector_type(4))) float floatx4;
typedef __attribute__((ext_vector_type(4))) unsigned int uint4v;

using bf16 = __hip_bfloat16;

#define DEVI __device__ __forceinline__

// ---------------- workspace layout (bytes) ----------------
static constexpr size_t OFF_SCORE  = 0;                        // 128*128 f32
static constexpr size_t OFF_FLAGS  = 65536;                    // 8*128*32 u32
static constexpr size_t OFF_CPUB0  = OFF_FLAGS  + 131072;      // 128*1024 bf16
static constexpr size_t OFF_CPUB1  = OFF_CPUB0  + 262144;
static constexpr size_t ZERO_BYTES = OFF_CPUB1;                // score+flags+Cpub0
static constexpr size_t OFF_G      = OFF_CPUB1  + 262144;      // 128*128 f32
static constexpr size_t OFF_BIASR  = OFF_G      + 65536;       // 1024 f32
static constexpr size_t OFF_CFIN   = OFF_BIASR  + 4096;        // 128*1024 f32
static constexpr size_t OFF_CONCAT = OFF_CFIN   + 524288;      // 128*3072 bf16
static constexpr size_t OFF_FACTS  = OFF_CONCAT + 786432;      // 16M bf16
static constexpr size_t OFF_WZ1    = OFF_FACTS  + 33554432ull; // 1024*4096 bf16
static constexpr size_t OFF_WRW    = OFF_WZ1    + 8388608ull;  // 2048*1024 bf16
static constexpr size_t OFF_URU    = OFF_WRW    + 4194304ull;  // 2048*1024 bf16
static constexpr size_t OFF_WM     = OFF_URU    + 4194304ull;  // 1024*3072 bf16
static constexpr size_t OFF_P      = OFF_WM     + 6291456ull;  // 128*128*2048 bf16

DEVI float sigm_f(float x){ return 1.f/(1.f + __expf(-x)); }
DEVI float tanh_f(float x){ float e = __expf(2.f*x); return 1.f - 2.f/(e + 1.f); }

// ---- coherent-point (sc0 sc1) data access helpers ----
DEVI unsigned long long ld_cg_u64(const unsigned long long* p){
  unsigned long long r;
  asm volatile("global_load_dwordx2 %0, %1, off sc0 sc1" : "=v"(r) : "v"(p) : "memory");
  return r;
}
DEVI void st_cg_u32(unsigned int* p, unsigned int v){
  asm volatile("global_store_dword %0, %1, off sc0 sc1" : : "v"(p), "v"(v) : "memory");
}
DEVI void waitcnt_vm0(){ asm volatile("s_waitcnt vmcnt(0)" ::: "memory"); }

// ---- async global -> LDS DMA. LDS base MUST be wave-uniform: HW writes
// lane i at lds_base + i*16. Passing a lane-varying pointer risks a
// waterfall lowering with double-offset LDS writes (R3 crash).
typedef const __attribute__((address_space(1))) unsigned int* as1_u32p;
typedef __attribute__((address_space(3))) unsigned int* as3_u32p;
DEVI void dma16(const void* g, void* lds_uniform_base){
  __builtin_amdgcn_global_load_lds((as1_u32p)g, (as3_u32p)lds_uniform_base, 16, 0, 0);
}

// ---------------- small utility kernels ----------------
__global__ void cast_f32_bf16(const float* __restrict__ src, bf16* __restrict__ dst, int n){
  int i = (blockIdx.x*256 + threadIdx.x)*4;
  if (i >= n) return;
  float4 v = *(const float4*)(src + i);
  union { bf16 h[4]; short4v s; } u;
  u.h[0] = __float2bfloat16(v.x); u.h[1] = __float2bfloat16(v.y);
  u.h[2] = __float2bfloat16(v.z); u.h[3] = __float2bfloat16(v.w);
  *(short4v*)(dst + i) = u.s;
}

__global__ void add_bias_k(const float* __restrict__ a, const float* __restrict__ b, float* __restrict__ o){
  int i = blockIdx.x*256 + threadIdx.x;
  if (i < 1024) o[i] = a[i] + b[i];
}

__global__ void softmax128(const float* __restrict__ score, float* __restrict__ G){
  int b = blockIdx.x, t = threadIdx.x;
  int lane = t & 63, wv = t >> 6;
  float v = score[b*128 + t];
  float mx = v;
  #pragma unroll
  for (int m = 1; m < 64; m <<= 1) mx = fmaxf(mx, __shfl_xor(mx, m));
  __shared__ float r1[2], r2[2];
  if (lane == 0) r1[wv] = mx;
  __syncthreads();
  mx = fmaxf(r1[0], r1[1]);
  float e = __expf(v - mx);
  float sm = e;
  #pragma unroll
  for (int m = 1; m < 64; m <<= 1) sm += __shfl_xor(sm, m);
  if (lane == 0) r2[wv] = sm;
  __syncthreads();
  sm = r2[0] + r2[1];
  G[b*128 + t] = e / sm;
}

__global__ void build_concat(const float* __restrict__ prevM, const float* __restrict__ Cfin,
                             const float* __restrict__ q, bf16* __restrict__ out){
  int i = (blockIdx.x*256 + threadIdx.x)*4;   // n = 128*3072
  if (i >= 128*3072) return;
  int b = i / 3072, k = i % 3072;
  const float* src = (k < 1024) ? (prevM + b*1024 + k)
                   : (k < 2048) ? (Cfin + b*1024 + (k-1024))
                                : (q    + b*1024 + (k-2048));
  float4 v = *(const float4*)src;
  union { bf16 h[4]; short4v s; } u;
  u.h[0] = __float2bfloat16(v.x); u.h[1] = __float2bfloat16(v.y);
  u.h[2] = __float2bfloat16(v.z); u.h[3] = __float2bfloat16(v.w);
  *(short4v*)(out + i) = u.s;
}

// ---------------- gate GEMM: z on-the-fly (A), DMA-staged B, fused epilogue ----------------
__global__ __launch_bounds__(256, 2) void gate_gemm(
    const float* __restrict__ facts, const float* __restrict__ q,
    const float* __restrict__ pm, const bf16* __restrict__ Wz1b,
    const float* __restrict__ bz1, const float* __restrict__ wz2,
    float* __restrict__ score)
{
  constexpr int TS = 80;                 // padded stride for the VALU-built A tile
  __shared__ alignas(16) bf16 As[128*TS];
  __shared__ alignas(16) bf16 Bs[128*64];  // k-slot-major [sl][row][8]
  __shared__ float qs[1024];
  __shared__ float ms[1024];
  int tid = threadIdx.x;
  int b  = blockIdx.y;
  int n0 = blockIdx.x * 128;
  int w = tid >> 6, lane = tid & 63;
  int wm = w >> 1, wn = w & 1;
  int quad = lane >> 4, col = lane & 15;

  for (int i = tid; i < 1024; i += 256){ qs[i] = q[b*1024 + i]; ms[i] = pm[b*1024 + i]; }
  __syncthreads();

  floatx4 acc[4][4];
  #pragma unroll
  for (int a = 0; a < 4; ++a)
    #pragma unroll
    for (int c = 0; c < 4; ++c) acc[a][c] = (floatx4){0.f,0.f,0.f,0.f};

  for (int it = 0; it < 64; ++it){
    int k0 = it * 64;
    int qd = k0 >> 10;
    int kk0 = k0 & 1023;
    // B tile: async DMA (uniform LDS chunk base), overlapped with A z-build
    #pragma unroll
    for (int i = 0; i < 4; ++i){
      int ch = w*4 + i;                  // 0..15
      int sl = ch >> 1, h = ch & 1;
      int row = h*64 + lane;
      dma16(Wz1b + (size_t)(n0 + row)*4096 + k0 + sl*8, Bs + ch*512);
    }
    // A tile: build z in VALU
    #pragma unroll
    for (int i = 0; i < 4; ++i){
      int c = tid + i*256;
      int r = c >> 3, cc = c & 7;
      int kk = kk0 + cc*8;
      const float* fp = facts + (size_t)(b*128 + r)*1024 + kk;
      float f[8], aux[8];
      *(float4*)(f)   = *(const float4*)(fp);
      *(float4*)(f+4) = *(const float4*)(fp + 4);
      const float* av = (qd == 0 || qd == 2) ? qs : ms;
      *(float4*)(aux)   = *(const float4*)(av + kk);
      *(float4*)(aux+4) = *(const float4*)(av + kk + 4);
      union { bf16 h[8]; short8 s8; } u;
      if (qd < 2){
        #pragma unroll
        for (int j = 0; j < 8; ++j) u.h[j] = __float2bfloat16(f[j]*aux[j]);
      } else {
        #pragma unroll
        for (int j = 0; j < 8; ++j) u.h[j] = __float2bfloat16(fabsf(f[j]-aux[j]));
      }
      *(short8*)&As[r*TS + cc*8] = u.s8;
    }
    waitcnt_vm0();
    __syncthreads();
    #pragma unroll
    for (int kt = 0; kt < 2; ++kt){
      short8 af[4], bfv[4];
      #pragma unroll
      for (int mt = 0; mt < 4; ++mt)
        af[mt] = *(const short8*)&As[(wm*64 + mt*16 + col)*TS + kt*32 + quad*8];
      #pragma unroll
      for (int nt = 0; nt < 4; ++nt)
        bfv[nt] = *(const short8*)&Bs[(kt*4 + quad)*1024 + (wn*64 + nt*16 + col)*8];
      #pragma unroll
      for (int mt = 0; mt < 4; ++mt)
        #pragma unroll
        for (int nt = 0; nt < 4; ++nt)
          acc[mt][nt] = __builtin_amdgcn_mfma_f32_16x16x32_bf16(af[mt], bfv[nt], acc[mt][nt], 0,0,0);
    }
    __syncthreads();
  }
  #pragma unroll
  for (int mt = 0; mt < 4; ++mt){
    float part[4] = {0.f,0.f,0.f,0.f};
    #pragma unroll
    for (int nt = 0; nt < 4; ++nt){
      int n = n0 + wn*64 + nt*16 + col;
      float b1 = bz1[n], w2 = wz2[n];
      #pragma unroll
      for (int rr = 0; rr < 4; ++rr)
        part[rr] += tanh_f(acc[mt][nt][rr] + b1) * w2;
    }
    #pragma unroll
    for (int rr = 0; rr < 4; ++rr){
      float p = part[rr];
      p += __shfl_xor(p, 1); p += __shfl_xor(p, 2);
      p += __shfl_xor(p, 4); p += __shfl_xor(p, 8);
      if (col == 0)
        atomicAdd(&score[b*128 + wm*64 + mt*16 + quad*4 + rr], p);
    }
  }
}

// ---------------- generic 128x128 bf16 GEMM (B^T), global_load_lds staging ----------------
// MODE 0: store P[s][b][n] bf16 (proj).  MODE 1: out = relu(acc + bias) fp32 (final).
template<int MODE>
__global__ __launch_bounds__(256, 2) void gemm_bt(
    const bf16* __restrict__ A, const bf16* __restrict__ Bm, int K,
    bf16* __restrict__ Pout, const float* __restrict__ bias, float* __restrict__ out)
{
  __shared__ alignas(16) bf16 As[128*64];  // k-slot-major [sl][row][8]
  __shared__ alignas(16) bf16 Bs[128*64];
  int tid = threadIdx.x;
  int m0 = blockIdx.y * 128, n0 = blockIdx.x * 128;
  int w = tid >> 6, lane = tid & 63;
  int wm = w >> 1, wn = w & 1;
  int quad = lane >> 4, col = lane & 15;

  floatx4 acc[4][4];
  #pragma unroll
  for (int a = 0; a < 4; ++a)
    #pragma unroll
    for (int c = 0; c < 4; ++c) acc[a][c] = (floatx4){0.f,0.f,0.f,0.f};

  int nkb = K >> 6;
  for (int it = 0; it < nkb; ++it){
    int k0 = it * 64;
    #pragma unroll
    for (int i = 0; i < 4; ++i){
      int ch = w*4 + i;                  // 0..15
      int sl = ch >> 1, h = ch & 1;
      int row = h*64 + lane;
      dma16(A  + (size_t)(m0 + row)*K + k0 + sl*8, As + ch*512);
      dma16(Bm + (size_t)(n0 + row)*K + k0 + sl*8, Bs + ch*512);
    }
    waitcnt_vm0();
    __syncthreads();
    #pragma unroll
    for (int kt = 0; kt < 2; ++kt){
      short8 af[4], bfv[4];
      #pragma unroll
      for (int mt = 0; mt < 4; ++mt)
        af[mt] = *(const short8*)&As[(kt*4 + quad)*1024 + (wm*64 + mt*16 + col)*8];
      #pragma unroll
      for (int nt = 0; nt < 4; ++nt)
        bfv[nt] = *(const short8*)&Bs[(kt*4 + quad)*1024 + (wn*64 + nt*16 + col)*8];
      #pragma unroll
      for (int mt = 0; mt < 4; ++mt)
        #pragma unroll
        for (int nt = 0; nt < 4; ++nt)
          acc[mt][nt] = __builtin_amdgcn_mfma_f32_16x16x32_bf16(af[mt], bfv[nt], acc[mt][nt], 0,0,0);
    }
    __syncthreads();
  }
  #pragma unroll
  for (int mt = 0; mt < 4; ++mt)
    #pragma unroll
    for (int nt = 0; nt < 4; ++nt)
      #pragma unroll
      for (int rr = 0; rr < 4; ++rr){
        int m = m0 + wm*64 + mt*16 + quad*4 + rr;
        int n = n0 + wn*64 + nt*16 + col;
        float v = acc[mt][nt][rr];
        if (MODE == 0){
          Pout[((size_t)(m & 127)*128 + (m >> 7))*2048 + n] = __float2bfloat16(v);
        } else {
          out[(size_t)m*1024 + n] = fmaxf(v + bias[n], 0.f);
        }
      }
}

// ---------------- the sequential scan ----------------
// 256 blocks = 8 batch-groups (16 batches) x 32 column-blocks (32 cols).
// Handshake: per-producer per-step flag array, zero RMWs. Flags via compiled
// relaxed agent atomics (R2-proven visibility); C data via sc0sc1 + vmcnt.
__global__ __launch_bounds__(256, 1) void scan_kernel(
    const bf16* __restrict__ UrU, const bf16* __restrict__ P,
    const float* __restrict__ G, const float* __restrict__ bias_r,
    const float* __restrict__ bw, const float* __restrict__ bu,
    bf16* __restrict__ Cpub, float* __restrict__ Cfinal,
    unsigned int* __restrict__ flags)
{
  constexpr int CS = 1040;               // padded LDS stride (bf16), 16B-aligned
  __shared__ alignas(16) bf16 Cs[16*CS];
  __shared__ float Qex[2*16*32];         // [matrix][batch][col]
  int tid = threadIdx.x;
  int g  = blockIdx.x >> 5;              // batch group 0..7
  int nb = blockIdx.x & 31;              // column block 0..31
  int b0 = g * 16, j0 = nb * 32;
  int w = tid >> 6, lane = tid & 63;
  int quad = lane >> 4, col = lane & 15;
  unsigned int* flg = flags + g*(128*32);

  // B-fragments in registers: wave w -> matrix (w>>1), n-half (w&1)
  short8 bfrag[32];
  {
    int n = ((w >> 1) << 10) + j0 + ((w & 1) << 4) + col;
    const bf16* src = UrU + (size_t)n*1024 + (quad << 3);
    #pragma unroll
    for (int kt = 0; kt < 32; ++kt) bfrag[kt] = *(const short8*)(src + kt*32);
  }

  int r  = tid >> 4;                     // batch row 0..15
  int jp = (tid & 15) * 2;               // col pair
  float c0 = 0.f, c1 = 0.f;
  float2 brv = *(const float2*)(bias_r + j0 + jp);
  float2 bwv = *(const float2*)(bw     + j0 + jp);
  float2 buv = *(const float2*)(bu     + j0 + jp);

  for (int s = 0; s < 128; ++s){
    // prefetch P/G for this step (independent of the handshake)
    const bf16* Ps = P + (size_t)s*(128*2048) + (size_t)(b0 + r)*2048 + j0 + jp;
    unsigned int up1 = *(const unsigned int*)Ps;
    unsigned int up2 = *(const unsigned int*)(Ps + 1024);
    float gg = G[(b0 + r)*128 + s];

    // ballot-poll: lanes 0..31 of EVERY wave each watch one producer flag;
    // wave exits when all 32 are set (no cross-wave dependency, no barrier).
    if (s){
      const unsigned int* myf = flg + ((s-1) << 5);
      for (;;){
        unsigned int f = (lane < 32)
          ? __hip_atomic_load(myf + lane, __ATOMIC_RELAXED, __HIP_MEMORY_SCOPE_AGENT)
          : 1u;
        if (__ballot(f == 0) == 0ull) break;
        __builtin_amdgcn_s_sleep(1);
      }
    }

    // stage this group's C (16 x 1024 bf16 = 4096 u64) from the coherent point
    const unsigned long long* Cg =
      (const unsigned long long*)(Cpub + (size_t)(s & 1)*(128*1024) + b0*1024);
    unsigned long long vv[16];
    #pragma unroll
    for (int i = 0; i < 16; ++i) vv[i] = ld_cg_u64(Cg + tid + i*256);
    waitcnt_vm0();
    #pragma unroll
    for (int i = 0; i < 16; ++i){
      int slot = tid + i*256;
      int rr = slot >> 8, cc = slot & 255;     // 256 u64 per row
      *(unsigned long long*)&Cs[rr*CS + cc*4] = vv[i];
    }
    __syncthreads();

    // Q = C @ [Ur;U]^T (this block's 32 cols), two independent MFMA chains
    floatx4 a0 = (floatx4){0.f,0.f,0.f,0.f}, a1 = (floatx4){0.f,0.f,0.f,0.f};
    {
      const bf16* Ap = Cs + col*CS + (quad << 3);
      #pragma unroll
      for (int kt = 0; kt < 16; ++kt){
        short8 a = *(const short8*)(Ap + kt*32);
        a0 = __builtin_amdgcn_mfma_f32_16x16x32_bf16(a, bfrag[kt], a0, 0,0,0);
      }
      #pragma unroll
      for (int kt = 16; kt < 32; ++kt){
        short8 a = *(const short8*)(Ap + kt*32);
        a1 = __builtin_amdgcn_mfma_f32_16x16x32_bf16(a, bfrag[kt], a1, 0,0,0);
      }
    }
    {
      int mi = w >> 1, nh = w & 1;
      #pragma unroll
      for (int rr = 0; rr < 4; ++rr)
        Qex[mi*512 + (quad*4 + rr)*32 + nh*16 + col] = a0[rr] + a1[rr];
    }
    __syncthreads();

    // elementwise GRU-style update: thread owns (batch r, cols jp,jp+1)
    float p1a = __bfloat162float(*(const bf16*)&up1);
    float p1b = __bfloat162float(*((const bf16*)&up1 + 1));
    float p2a = __bfloat162float(*(const bf16*)&up2);
    float p2b = __bfloat162float(*((const bf16*)&up2 + 1));
    float2 q1 = *(const float2*)&Qex[r*32 + jp];
    float2 q2 = *(const float2*)&Qex[512 + r*32 + jp];
    float ra = sigm_f(p1a + q1.x + brv.x);
    float ha = tanh_f(p2a + bwv.x + ra*(q2.x + buv.x));
    c0 = gg*ha + (1.f - gg)*c0;
    float rb = sigm_f(p1b + q1.y + brv.y);
    float hb = tanh_f(p2b + bwv.y + rb*(q2.y + buv.y));
    c1 = gg*hb + (1.f - gg)*c1;

    if (s != 127){
      union { bf16 h[2]; unsigned int u; } pk;
      pk.h[0] = __float2bfloat16(c0);
      pk.h[1] = __float2bfloat16(c1);
      unsigned int* dst = (unsigned int*)
        (Cpub + (size_t)((s & 1) ^ 1)*(128*1024) + (size_t)(b0 + r)*1024 + j0 + jp);
      st_cg_u32(dst, pk.u);
      waitcnt_vm0();                      // this thread's store ack'd at coherent point
      __syncthreads();                    // whole block published (also guards Cs/Qex reuse)
      if (tid == 0)
        __hip_atomic_store(&flg[(s << 5) + nb], 1u, __ATOMIC_RELAXED, __HIP_MEMORY_SCOPE_AGENT);
    }
  }
  *(float2*)&Cfinal[(size_t)(b0 + r)*1024 + j0 + jp] = make_float2(c0, c1);
}

// ---------------- host launch ----------------
extern "C" void kernel_launch(void* const* d_in, const int* in_sizes, int n_in,
                              void* d_out, int out_size, void* d_ws, size_t ws_size,
                              hipStream_t stream) {
  const float* facts     = (const float*)d_in[0];
  const float* questions = (const float*)d_in[1];
  const float* prevM     = (const float*)d_in[2];
  const float* Wr        = (const float*)d_in[3];
  const float* br        = (const float*)d_in[4];
  const float* Ur        = (const float*)d_in[5];
  const float* bur       = (const float*)d_in[6];
  const float* Wf        = (const float*)d_in[7];
  const float* bw        = (const float*)d_in[8];
  const float* U         = (const float*)d_in[9];
  const float* bu        = (const float*)d_in[10];
  const float* Wz1       = (const float*)d_in[11];
  const float* bz1       = (const float*)d_in[12];
  const float* Wz2       = (const float*)d_in[13];
  const float* Wm        = (const float*)d_in[15];
  const float* bm        = (const float*)d_in[16];
  float* out = (float*)d_out;

  char* ws = (char*)d_ws;
  float*        score   = (float*)(ws + OFF_SCORE);
  unsigned int* flags   = (unsigned int*)(ws + OFF_FLAGS);
  bf16*         Cpub    = (bf16*)(ws + OFF_CPUB0);
  float*        G       = (float*)(ws + OFF_G);
  float*        bias_r  = (float*)(ws + OFF_BIASR);
  float*        Cfin    = (float*)(ws + OFF_CFIN);
  bf16*         concat  = (bf16*)(ws + OFF_CONCAT);
  bf16*         facts_b = (bf16*)(ws + OFF_FACTS);
  bf16*         Wz1_b   = (bf16*)(ws + OFF_WZ1);
  bf16*         WrW_b   = (bf16*)(ws + OFF_WRW);
  bf16*         UrU_b   = (bf16*)(ws + OFF_URU);
  bf16*         Wm_b    = (bf16*)(ws + OFF_WM);
  bf16*         P       = (bf16*)(ws + OFF_P);

  hipMemsetAsync(ws, 0, ZERO_BYTES, stream);

  cast_f32_bf16<<<16384, 256, 0, stream>>>(facts, facts_b, 16777216);
  cast_f32_bf16<<< 4096, 256, 0, stream>>>(Wz1, Wz1_b, 4194304);
  cast_f32_bf16<<< 1024, 256, 0, stream>>>(Wr, WrW_b,           1048576);
  cast_f32_bf16<<< 1024, 256, 0, stream>>>(Wf, WrW_b + 1048576, 1048576);
  cast_f32_bf16<<< 1024, 256, 0, stream>>>(Ur, UrU_b,           1048576);
  cast_f32_bf16<<< 1024, 256, 0, stream>>>(U,  UrU_b + 1048576, 1048576);
  cast_f32_bf16<<< 3072, 256, 0, stream>>>(Wm, Wm_b, 3145728);
  add_bias_k<<<4, 256, 0, stream>>>(br, bur, bias_r);

  gate_gemm<<<dim3(8, 128), 256, 0, stream>>>(facts, questions, prevM, Wz1_b, bz1, Wz2, score);
  softmax128<<<128, 128, 0, stream>>>(score, G);

  gemm_bt<0><<<dim3(16, 128), 256, 0, stream>>>(facts_b, WrW_b, 1024, P, nullptr, nullptr);

  scan_kernel<<<256, 256, 0, stream>>>(UrU_b, P, G, bias_r, bw, bu, Cpub, Cfin, flags);

  build_concat<<<384, 256, 0, stream>>>(prevM, Cfin, questions, concat);
  gemm_bt<1><<<dim3(8, 1), 256, 0, stream>>>(concat, Wm_b, 3072, nullptr, bm, out);
}

// Round 6
// 1157.750 us; speedup vs baseline: 1.0410x; 1.0410x over previous
//
#include <hip/hip_runtime.h>
#include <hip/hip_bf16.h>

typedef __attribute__((ext_vector_type(8))) short short8;
typedef __attribute__((ext_vector_type(4))) short short4v;
typedef __attribute__((ext_vector_type(4))) float floatx4;
typedef __attribute__((ext_vector_type(4))) unsigned int uint4v;

using bf16 = __hip_bfloat16;

#define DEVI __device__ __forceinline__

// ---------------- workspace layout (bytes) ----------------
static constexpr size_t OFF_SCORE  = 0;                        // 128*128 f32
static constexpr size_t OFF_CPUB   = 65536;                    // 2 x (128*512 u64) epoch-tagged C
static constexpr size_t ZERO_BYTES = 65536 + 524288;           // score + Cpub buf0 (epoch 0 == C0 = 0)
static constexpr size_t OFF_G      = OFF_CPUB   + 1048576;     // 128*128 f32
static constexpr size_t OFF_BIASR  = OFF_G      + 65536;       // 1024 f32
static constexpr size_t OFF_CFIN   = OFF_BIASR  + 4096;        // 128*1024 f32
static constexpr size_t OFF_CONCAT = OFF_CFIN   + 524288;      // 128*3072 bf16
static constexpr size_t OFF_FACTS  = OFF_CONCAT + 786432;      // 16M bf16
static constexpr size_t OFF_WZ1    = OFF_FACTS  + 33554432ull; // 1024*4096 bf16
static constexpr size_t OFF_WRW    = OFF_WZ1    + 8388608ull;  // 2048*1024 bf16
static constexpr size_t OFF_URU    = OFF_WRW    + 4194304ull;  // 2048*1024 bf16
static constexpr size_t OFF_WM     = OFF_URU    + 4194304ull;  // 1024*3072 bf16
static constexpr size_t OFF_P      = OFF_WM     + 6291456ull;  // 128*128*2048 bf16

DEVI float sigm_f(float x){ return 1.f/(1.f + __expf(-x)); }
DEVI float tanh_f(float x){ float e = __expf(2.f*x); return 1.f - 2.f/(e + 1.f); }

// ---- coherent-point (sc0 sc1) access helpers ----
DEVI uint4v ld_cg_u128(const uint4v* p){
  uint4v r;
  asm volatile("global_load_dwordx4 %0, %1, off sc0 sc1" : "=v"(r) : "v"(p) : "memory");
  return r;
}
DEVI void st_cg_u64(unsigned long long* p, unsigned long long v){
  asm volatile("global_store_dwordx2 %0, %1, off sc0 sc1" : : "v"(p), "v"(v) : "memory");
}
DEVI void waitcnt_vm0(){ asm volatile("s_waitcnt vmcnt(0)" ::: "memory"); }

// ---------------- small utility kernels ----------------
__global__ void cast_f32_bf16(const float* __restrict__ src, bf16* __restrict__ dst, int n){
  int i = (blockIdx.x*256 + threadIdx.x)*4;
  if (i >= n) return;
  float4 v = *(const float4*)(src + i);
  union { bf16 h[4]; short4v s; } u;
  u.h[0] = __float2bfloat16(v.x); u.h[1] = __float2bfloat16(v.y);
  u.h[2] = __float2bfloat16(v.z); u.h[3] = __float2bfloat16(v.w);
  *(short4v*)(dst + i) = u.s;
}

__global__ void add_bias_k(const float* __restrict__ a, const float* __restrict__ b, float* __restrict__ o){
  int i = blockIdx.x*256 + threadIdx.x;
  if (i < 1024) o[i] = a[i] + b[i];
}

__global__ void softmax128(const float* __restrict__ score, float* __restrict__ G){
  int b = blockIdx.x, t = threadIdx.x;
  int lane = t & 63, wv = t >> 6;
  float v = score[b*128 + t];
  float mx = v;
  #pragma unroll
  for (int m = 1; m < 64; m <<= 1) mx = fmaxf(mx, __shfl_xor(mx, m));
  __shared__ float r1[2], r2[2];
  if (lane == 0) r1[wv] = mx;
  __syncthreads();
  mx = fmaxf(r1[0], r1[1]);
  float e = __expf(v - mx);
  float sm = e;
  #pragma unroll
  for (int m = 1; m < 64; m <<= 1) sm += __shfl_xor(sm, m);
  if (lane == 0) r2[wv] = sm;
  __syncthreads();
  sm = r2[0] + r2[1];
  G[b*128 + t] = e / sm;
}

__global__ void build_concat(const float* __restrict__ prevM, const float* __restrict__ Cfin,
                             const float* __restrict__ q, bf16* __restrict__ out){
  int i = (blockIdx.x*256 + threadIdx.x)*4;   // n = 128*3072
  if (i >= 128*3072) return;
  int b = i / 3072, k = i % 3072;
  const float* src = (k < 1024) ? (prevM + b*1024 + k)
                   : (k < 2048) ? (Cfin + b*1024 + (k-1024))
                                : (q    + b*1024 + (k-2048));
  float4 v = *(const float4*)src;
  union { bf16 h[4]; short4v s; } u;
  u.h[0] = __float2bfloat16(v.x); u.h[1] = __float2bfloat16(v.y);
  u.h[2] = __float2bfloat16(v.z); u.h[3] = __float2bfloat16(v.w);
  *(short4v*)(out + i) = u.s;
}

// ---------------- gate GEMM (R2-proven form): z on-the-fly, fused epilogue ----------------
__global__ __launch_bounds__(256, 2) void gate_gemm(
    const float* __restrict__ facts, const float* __restrict__ q,
    const float* __restrict__ pm, const bf16* __restrict__ Wz1b,
    const float* __restrict__ bz1, const float* __restrict__ wz2,
    float* __restrict__ score)
{
  constexpr int TS = 80;
  __shared__ bf16 As[128*TS];
  __shared__ bf16 Bs[128*TS];
  __shared__ float qs[1024];
  __shared__ float ms[1024];
  int tid = threadIdx.x;
  int b  = blockIdx.y;
  int n0 = blockIdx.x * 128;
  int w = tid >> 6, lane = tid & 63;
  int wm = w >> 1, wn = w & 1;
  int quad = lane >> 4, col = lane & 15;

  for (int i = tid; i < 1024; i += 256){ qs[i] = q[b*1024 + i]; ms[i] = pm[b*1024 + i]; }
  __syncthreads();

  floatx4 acc[4][4];
  #pragma unroll
  for (int a = 0; a < 4; ++a)
    #pragma unroll
    for (int c = 0; c < 4; ++c) acc[a][c] = (floatx4){0.f,0.f,0.f,0.f};

  for (int it = 0; it < 64; ++it){
    int k0 = it * 64;
    int qd = k0 >> 10;
    int kk0 = k0 & 1023;
    #pragma unroll
    for (int i = 0; i < 4; ++i){
      int c = tid + i*256;
      int r = c >> 3, cc = c & 7;
      int kk = kk0 + cc*8;
      const float* fp = facts + (size_t)(b*128 + r)*1024 + kk;
      float f[8], aux[8];
      *(float4*)(f)   = *(const float4*)(fp);
      *(float4*)(f+4) = *(const float4*)(fp + 4);
      const float* av = (qd == 0 || qd == 2) ? qs : ms;
      *(float4*)(aux)   = *(const float4*)(av + kk);
      *(float4*)(aux+4) = *(const float4*)(av + kk + 4);
      union { bf16 h[8]; short8 s8; } u;
      if (qd < 2){
        #pragma unroll
        for (int j = 0; j < 8; ++j) u.h[j] = __float2bfloat16(f[j]*aux[j]);
      } else {
        #pragma unroll
        for (int j = 0; j < 8; ++j) u.h[j] = __float2bfloat16(fabsf(f[j]-aux[j]));
      }
      *(short8*)&As[r*TS + cc*8] = u.s8;
    }
    #pragma unroll
    for (int i = 0; i < 4; ++i){
      int c = tid + i*256;
      int r = c >> 3, cc = c & 7;
      *(uint4v*)&Bs[r*TS + cc*8] = *(const uint4v*)(Wz1b + (size_t)(n0 + r)*4096 + k0 + cc*8);
    }
    __syncthreads();
    #pragma unroll
    for (int kt = 0; kt < 2; ++kt){
      short8 af[4], bfv[4];
      #pragma unroll
      for (int mt = 0; mt < 4; ++mt)
        af[mt] = *(const short8*)&As[(wm*64 + mt*16 + col)*TS + kt*32 + quad*8];
      #pragma unroll
      for (int nt = 0; nt < 4; ++nt)
        bfv[nt] = *(const short8*)&Bs[(wn*64 + nt*16 + col)*TS + kt*32 + quad*8];
      #pragma unroll
      for (int mt = 0; mt < 4; ++mt)
        #pragma unroll
        for (int nt = 0; nt < 4; ++nt)
          acc[mt][nt] = __builtin_amdgcn_mfma_f32_16x16x32_bf16(af[mt], bfv[nt], acc[mt][nt], 0,0,0);
    }
    __syncthreads();
  }
  #pragma unroll
  for (int mt = 0; mt < 4; ++mt){
    float part[4] = {0.f,0.f,0.f,0.f};
    #pragma unroll
    for (int nt = 0; nt < 4; ++nt){
      int n = n0 + wn*64 + nt*16 + col;
      float b1 = bz1[n], w2 = wz2[n];
      #pragma unroll
      for (int rr = 0; rr < 4; ++rr)
        part[rr] += tanh_f(acc[mt][nt][rr] + b1) * w2;
    }
    #pragma unroll
    for (int rr = 0; rr < 4; ++rr){
      float p = part[rr];
      p += __shfl_xor(p, 1); p += __shfl_xor(p, 2);
      p += __shfl_xor(p, 4); p += __shfl_xor(p, 8);
      if (col == 0)
        atomicAdd(&score[b*128 + wm*64 + mt*16 + quad*4 + rr], p);
    }
  }
}

// ---------------- generic 128x128 bf16 GEMM (B^T layout, R2-proven form) ----------------
template<int MODE>
__global__ __launch_bounds__(256, 2) void gemm_bt(
    const bf16* __restrict__ A, const bf16* __restrict__ Bm, int K,
    bf16* __restrict__ Pout, const float* __restrict__ bias, float* __restrict__ out)
{
  constexpr int TS = 80;
  __shared__ bf16 As[128*TS];
  __shared__ bf16 Bs[128*TS];
  int tid = threadIdx.x;
  int m0 = blockIdx.y * 128, n0 = blockIdx.x * 128;
  int w = tid >> 6, lane = tid & 63;
  int wm = w >> 1, wn = w & 1;
  int quad = lane >> 4, col = lane & 15;

  floatx4 acc[4][4];
  #pragma unroll
  for (int a = 0; a < 4; ++a)
    #pragma unroll
    for (int c = 0; c < 4; ++c) acc[a][c] = (floatx4){0.f,0.f,0.f,0.f};

  int nkb = K >> 6;
  for (int it = 0; it < nkb; ++it){
    int k0 = it * 64;
    #pragma unroll
    for (int i = 0; i < 4; ++i){
      int c = tid + i*256;
      int r = c >> 3, cc = c & 7;
      *(uint4v*)&As[r*TS + cc*8] = *(const uint4v*)(A  + (size_t)(m0 + r)*K + k0 + cc*8);
      *(uint4v*)&Bs[r*TS + cc*8] = *(const uint4v*)(Bm + (size_t)(n0 + r)*K + k0 + cc*8);
    }
    __syncthreads();
    #pragma unroll
    for (int kt = 0; kt < 2; ++kt){
      short8 af[4], bfv[4];
      #pragma unroll
      for (int mt = 0; mt < 4; ++mt)
        af[mt] = *(const short8*)&As[(wm*64 + mt*16 + col)*TS + kt*32 + quad*8];
      #pragma unroll
      for (int nt = 0; nt < 4; ++nt)
        bfv[nt] = *(const short8*)&Bs[(wn*64 + nt*16 + col)*TS + kt*32 + quad*8];
      #pragma unroll
      for (int mt = 0; mt < 4; ++mt)
        #pragma unroll
        for (int nt = 0; nt < 4; ++nt)
          acc[mt][nt] = __builtin_amdgcn_mfma_f32_16x16x32_bf16(af[mt], bfv[nt], acc[mt][nt], 0,0,0);
    }
    __syncthreads();
  }
  #pragma unroll
  for (int mt = 0; mt < 4; ++mt)
    #pragma unroll
    for (int nt = 0; nt < 4; ++nt)
      #pragma unroll
      for (int rr = 0; rr < 4; ++rr){
        int m = m0 + wm*64 + mt*16 + quad*4 + rr;
        int n = n0 + wn*64 + nt*16 + col;
        float v = acc[mt][nt][rr];
        if (MODE == 0){
          Pout[((size_t)(m & 127)*128 + (m >> 7))*2048 + n] = __float2bfloat16(v);
        } else {
          out[(size_t)m*1024 + n] = fmaxf(v + bias[n], 0.f);
        }
      }
}

// ---------------- the sequential scan ----------------
// 256 blocks = 8 batch-groups (16 batches) x 32 column-blocks (32 cols).
// Epoch-tagged publish: each col-pair is a u64 {epoch, bf16x2} at the
// coherent point. Consumers poll the DATA (accept when epoch==s) — no flags,
// no producer ack, no fences, 2 barriers/step. Double buffer keeps the old
// epoch readable; 0xAA poison can never alias an epoch in [0,128).
__global__ __launch_bounds__(256, 1) void scan_kernel(
    const bf16* __restrict__ UrU, const bf16* __restrict__ P,
    const float* __restrict__ G, const float* __restrict__ bias_r,
    const float* __restrict__ bw, const float* __restrict__ bu,
    unsigned long long* __restrict__ Cpub, float* __restrict__ Cfinal)
{
  constexpr int CS = 1040;               // padded LDS stride (bf16), 16B-aligned
  __shared__ bf16 Cs[16*CS];
  __shared__ float Qex[2*16*32];         // [matrix][batch][col]
  int tid = threadIdx.x;
  int g  = blockIdx.x >> 5;              // batch group 0..7
  int nb = blockIdx.x & 31;              // column block 0..31
  int b0 = g * 16, j0 = nb * 32;
  int w = tid >> 6, lane = tid & 63;
  int quad = lane >> 4, col = lane & 15;

  // B-fragments in registers: wave w -> matrix (w>>1), n-half (w&1)
  short8 bfrag[32];
  {
    int n = ((w >> 1) << 10) + j0 + ((w & 1) << 4) + col;
    const bf16* src = UrU + (size_t)n*1024 + (quad << 3);
    #pragma unroll
    for (int kt = 0; kt < 32; ++kt) bfrag[kt] = *(const short8*)(src + kt*32);
  }

  int r  = tid >> 4;                     // batch row 0..15
  int jp = (tid & 15) * 2;               // col pair
  float c0 = 0.f, c1 = 0.f;
  float2 brv = *(const float2*)(bias_r + j0 + jp);
  float2 bwv = *(const float2*)(bw     + j0 + jp);
  float2 buv = *(const float2*)(bu     + j0 + jp);

  for (int s = 0; s < 128; ++s){
    // prefetch P/G for this step (independent of the handshake)
    const bf16* Ps = P + (size_t)s*(128*2048) + (size_t)(b0 + r)*2048 + j0 + jp;
    unsigned int up1 = *(const unsigned int*)Ps;
    unsigned int up2 = *(const unsigned int*)(Ps + 1024);
    float gg = G[(b0 + r)*128 + s];

    // poll-the-data: this group's C = 16 x 512 tagged u64 = 4096 dwordx4.
    // Accept when every high word carries epoch s. Detection returns the data.
    const uint4v* Cg = (const uint4v*)
      (Cpub + (size_t)(s & 1)*65536 + (size_t)b0*512);
    uint4v vv[16];
    unsigned int expct = (unsigned int)s;
    for (;;){
      #pragma unroll
      for (int i = 0; i < 16; ++i) vv[i] = ld_cg_u128(Cg + tid + i*256);
      waitcnt_vm0();
      unsigned int bad = 0;
      #pragma unroll
      for (int i = 0; i < 16; ++i)
        bad |= (vv[i].y ^ expct) | (vv[i].w ^ expct);
      if (__ballot(bad != 0u) == 0ull) break;
      __builtin_amdgcn_s_sleep(1);
    }
    #pragma unroll
    for (int i = 0; i < 16; ++i){
      int p = tid + i*256;               // pair-of-u64 index 0..4095
      int rr = p >> 8, pi = p & 255;     // 256 pairs per batch row
      unsigned long long wdat = (unsigned long long)vv[i].x
                              | ((unsigned long long)vv[i].z << 32);
      *(unsigned long long*)&Cs[rr*CS + pi*4] = wdat;   // 4 bf16 cols
    }
    __syncthreads();                     // barrier #1: Cs ready (also orders vs prev-iter Qex reads)

    // Q = C @ [Ur;U]^T (this block's 32 cols), two independent MFMA chains
    floatx4 a0 = (floatx4){0.f,0.f,0.f,0.f}, a1 = (floatx4){0.f,0.f,0.f,0.f};
    {
      const bf16* Ap = Cs + col*CS + (quad << 3);
      #pragma unroll
      for (int kt = 0; kt < 16; ++kt){
        short8 a = *(const short8*)(Ap + kt*32);
        a0 = __builtin_amdgcn_mfma_f32_16x16x32_bf16(a, bfrag[kt], a0, 0,0,0);
      }
      #pragma unroll
      for (int kt = 16; kt < 32; ++kt){
        short8 a = *(const short8*)(Ap + kt*32);
        a1 = __builtin_amdgcn_mfma_f32_16x16x32_bf16(a, bfrag[kt], a1, 0,0,0);
      }
    }
    {
      int mi = w >> 1, nh = w & 1;
      #pragma unroll
      for (int rr = 0; rr < 4; ++rr)
        Qex[mi*512 + (quad*4 + rr)*32 + nh*16 + col] = a0[rr] + a1[rr];
    }
    __syncthreads();                     // barrier #2: Qex ready (Cs reads all done)

    // elementwise GRU-style update: thread owns (batch r, cols jp,jp+1)
    float p1a = __bfloat162float(*(const bf16*)&up1);
    float p1b = __bfloat162float(*((const bf16*)&up1 + 1));
    float p2a = __bfloat162float(*(const bf16*)&up2);
    float p2b = __bfloat162float(*((const bf16*)&up2 + 1));
    float2 q1 = *(const float2*)&Qex[r*32 + jp];
    float2 q2 = *(const float2*)&Qex[512 + r*32 + jp];
    float ra = sigm_f(p1a + q1.x + brv.x);
    float ha = tanh_f(p2a + bwv.x + ra*(q2.x + buv.x));
    c0 = gg*ha + (1.f - gg)*c0;
    float rb = sigm_f(p1b + q1.y + brv.y);
    float hb = tanh_f(p2b + bwv.y + rb*(q2.y + buv.y));
    c1 = gg*hb + (1.f - gg)*c1;

    // publish tagged {epoch=s+1, c0,c1}; no ack, no flag, no barrier.
    // Next-iter barrier #1 protects LDS; the poll's waitcnt drains this store.
    if (s != 127){
      union { bf16 h[2]; unsigned int u; } pk;
      pk.h[0] = __float2bfloat16(c0);
      pk.h[1] = __float2bfloat16(c1);
      unsigned long long wd = ((unsigned long long)(unsigned int)(s + 1) << 32)
                            | (unsigned long long)pk.u;
      unsigned long long* dst = Cpub + (size_t)((s & 1) ^ 1)*65536
                              + (size_t)(b0 + r)*512 + ((j0 + jp) >> 1);
      st_cg_u64(dst, wd);
    }
  }
  *(float2*)&Cfinal[(size_t)(b0 + r)*1024 + j0 + jp] = make_float2(c0, c1);
}

// ---------------- host launch ----------------
extern "C" void kernel_launch(void* const* d_in, const int* in_sizes, int n_in,
                              void* d_out, int out_size, void* d_ws, size_t ws_size,
                              hipStream_t stream) {
  const float* facts     = (const float*)d_in[0];
  const float* questions = (const float*)d_in[1];
  const float* prevM     = (const float*)d_in[2];
  const float* Wr        = (const float*)d_in[3];
  const float* br        = (const float*)d_in[4];
  const float* Ur        = (const float*)d_in[5];
  const float* bur       = (const float*)d_in[6];
  const float* Wf        = (const float*)d_in[7];
  const float* bw        = (const float*)d_in[8];
  const float* U         = (const float*)d_in[9];
  const float* bu        = (const float*)d_in[10];
  const float* Wz1       = (const float*)d_in[11];
  const float* bz1       = (const float*)d_in[12];
  const float* Wz2       = (const float*)d_in[13];
  const float* Wm        = (const float*)d_in[15];
  const float* bm        = (const float*)d_in[16];
  float* out = (float*)d_out;

  char* ws = (char*)d_ws;
  float*              score   = (float*)(ws + OFF_SCORE);
  unsigned long long* Cpub    = (unsigned long long*)(ws + OFF_CPUB);
  float*              G       = (float*)(ws + OFF_G);
  float*              bias_r  = (float*)(ws + OFF_BIASR);
  float*              Cfin    = (float*)(ws + OFF_CFIN);
  bf16*               concat  = (bf16*)(ws + OFF_CONCAT);
  bf16*               facts_b = (bf16*)(ws + OFF_FACTS);
  bf16*               Wz1_b   = (bf16*)(ws + OFF_WZ1);
  bf16*               WrW_b   = (bf16*)(ws + OFF_WRW);
  bf16*               UrU_b   = (bf16*)(ws + OFF_URU);
  bf16*               Wm_b    = (bf16*)(ws + OFF_WM);
  bf16*               P       = (bf16*)(ws + OFF_P);

  hipMemsetAsync(ws, 0, ZERO_BYTES, stream);   // score + Cpub buf0 (epoch0 / C=0)

  cast_f32_bf16<<<16384, 256, 0, stream>>>(facts, facts_b, 16777216);
  cast_f32_bf16<<< 4096, 256, 0, stream>>>(Wz1, Wz1_b, 4194304);
  cast_f32_bf16<<< 1024, 256, 0, stream>>>(Wr, WrW_b,           1048576);
  cast_f32_bf16<<< 1024, 256, 0, stream>>>(Wf, WrW_b + 1048576, 1048576);
  cast_f32_bf16<<< 1024, 256, 0, stream>>>(Ur, UrU_b,           1048576);
  cast_f32_bf16<<< 1024, 256, 0, stream>>>(U,  UrU_b + 1048576, 1048576);
  cast_f32_bf16<<< 3072, 256, 0, stream>>>(Wm, Wm_b, 3145728);
  add_bias_k<<<4, 256, 0, stream>>>(br, bur, bias_r);

  gate_gemm<<<dim3(8, 128), 256, 0, stream>>>(facts, questions, prevM, Wz1_b, bz1, Wz2, score);
  softmax128<<<128, 128, 0, stream>>>(score, G);

  gemm_bt<0><<<dim3(16, 128), 256, 0, stream>>>(facts_b, WrW_b, 1024, P, nullptr, nullptr);

  scan_kernel<<<256, 256, 0, stream>>>(UrU_b, P, G, bias_r, bw, bu, Cpub, Cfin);

  build_concat<<<384, 256, 0, stream>>>(prevM, Cfin, questions, concat);
  gemm_bt<1><<<dim3(8, 1), 256, 0, stream>>>(concat, Wm_b, 3072, nullptr, bm, out);
}

// Round 7
// 1037.456 us; speedup vs baseline: 1.1617x; 1.1160x over previous
//
#include <hip/hip_runtime.h>
#include <hip/hip_bf16.h>

typedef __attribute__((ext_vector_type(8))) short short8;
typedef __attribute__((ext_vector_type(4))) short short4v;
typedef __attribute__((ext_vector_type(4))) float floatx4;
typedef __attribute__((ext_vector_type(4))) unsigned int uint4v;

using bf16 = __hip_bfloat16;

#define DEVI __device__ __forceinline__

// ---------------- workspace layout (bytes) ----------------
static constexpr size_t OFF_SCORE  = 0;                        // 128*128 f32
static constexpr size_t OFF_XCC    = 65536;                    // 8 groups * 32 slots u32 (+pad)
static constexpr size_t OFF_CPUB   = OFF_XCC + 4096;           // 2 x (128*512 u64) epoch-tagged C
static constexpr size_t ZERO_BYTES = OFF_CPUB + 524288;        // score + xcc + Cpub buf0 (epoch0 == C0=0)
static constexpr size_t OFF_G      = OFF_CPUB   + 1048576;     // 128*128 f32
static constexpr size_t OFF_BIASR  = OFF_G      + 65536;       // 1024 f32
static constexpr size_t OFF_CFIN   = OFF_BIASR  + 4096;        // 128*1024 f32
static constexpr size_t OFF_CONCAT = OFF_CFIN   + 524288;      // 128*3072 bf16
static constexpr size_t OFF_FACTS  = OFF_CONCAT + 786432;      // 16M bf16
static constexpr size_t OFF_WZ1    = OFF_FACTS  + 33554432ull; // 1024*4096 bf16
static constexpr size_t OFF_WRW    = OFF_WZ1    + 8388608ull;  // 2048*1024 bf16
static constexpr size_t OFF_URU    = OFF_WRW    + 4194304ull;  // 2048*1024 bf16
static constexpr size_t OFF_WM     = OFF_URU    + 4194304ull;  // 1024*3072 bf16
static constexpr size_t OFF_P      = OFF_WM     + 6291456ull;  // 128*128*2048 bf16

DEVI float sigm_f(float x){ return 1.f/(1.f + __expf(-x)); }
DEVI float tanh_f(float x){ float e = __expf(2.f*x); return 1.f - 2.f/(e + 1.f); }

// ---- coherence-tiered access helpers ----
// slow tier (cross-XCD): sc0 sc1 -> die-level coherent point (R6-proven)
// fast tier (same-XCD):  plain store (lands in this XCD's L2) + sc0 load
//                        (bypasses L1, served by the same L2) — L2 RTT ~200cyc
DEVI uint4v ld_cg_u128(const uint4v* p){
  uint4v r;
  asm volatile("global_load_dwordx4 %0, %1, off sc0 sc1" : "=v"(r) : "v"(p) : "memory");
  return r;
}
DEVI uint4v ld_l2_u128(const uint4v* p){
  uint4v r;
  asm volatile("global_load_dwordx4 %0, %1, off sc0" : "=v"(r) : "v"(p) : "memory");
  return r;
}
DEVI void st_cg_u64(unsigned long long* p, unsigned long long v){
  asm volatile("global_store_dwordx2 %0, %1, off sc0 sc1" : : "v"(p), "v"(v) : "memory");
}
DEVI void st_l2_u64(unsigned long long* p, unsigned long long v){
  asm volatile("global_store_dwordx2 %0, %1, off" : : "v"(p), "v"(v) : "memory");
}
DEVI void waitcnt_vm0(){ asm volatile("s_waitcnt vmcnt(0)" ::: "memory"); }

// ---------------- small utility kernels ----------------
__global__ void cast_f32_bf16(const float* __restrict__ src, bf16* __restrict__ dst, int n){
  int i = (blockIdx.x*256 + threadIdx.x)*4;
  if (i >= n) return;
  float4 v = *(const float4*)(src + i);
  union { bf16 h[4]; short4v s; } u;
  u.h[0] = __float2bfloat16(v.x); u.h[1] = __float2bfloat16(v.y);
  u.h[2] = __float2bfloat16(v.z); u.h[3] = __float2bfloat16(v.w);
  *(short4v*)(dst + i) = u.s;
}

__global__ void add_bias_k(const float* __restrict__ a, const float* __restrict__ b, float* __restrict__ o){
  int i = blockIdx.x*256 + threadIdx.x;
  if (i < 1024) o[i] = a[i] + b[i];
}

__global__ void softmax128(const float* __restrict__ score, float* __restrict__ G){
  int b = blockIdx.x, t = threadIdx.x;
  int lane = t & 63, wv = t >> 6;
  float v = score[b*128 + t];
  float mx = v;
  #pragma unroll
  for (int m = 1; m < 64; m <<= 1) mx = fmaxf(mx, __shfl_xor(mx, m));
  __shared__ float r1[2], r2[2];
  if (lane == 0) r1[wv] = mx;
  __syncthreads();
  mx = fmaxf(r1[0], r1[1]);
  float e = __expf(v - mx);
  float sm = e;
  #pragma unroll
  for (int m = 1; m < 64; m <<= 1) sm += __shfl_xor(sm, m);
  if (lane == 0) r2[wv] = sm;
  __syncthreads();
  sm = r2[0] + r2[1];
  G[b*128 + t] = e / sm;
}

__global__ void build_concat(const float* __restrict__ prevM, const float* __restrict__ Cfin,
                             const float* __restrict__ q, bf16* __restrict__ out){
  int i = (blockIdx.x*256 + threadIdx.x)*4;   // n = 128*3072
  if (i >= 128*3072) return;
  int b = i / 3072, k = i % 3072;
  const float* src = (k < 1024) ? (prevM + b*1024 + k)
                   : (k < 2048) ? (Cfin + b*1024 + (k-1024))
                                : (q    + b*1024 + (k-2048));
  float4 v = *(const float4*)src;
  union { bf16 h[4]; short4v s; } u;
  u.h[0] = __float2bfloat16(v.x); u.h[1] = __float2bfloat16(v.y);
  u.h[2] = __float2bfloat16(v.z); u.h[3] = __float2bfloat16(v.w);
  *(short4v*)(out + i) = u.s;
}

// ---------------- gate GEMM (R2-proven form): z on-the-fly, fused epilogue ----------------
__global__ __launch_bounds__(256, 2) void gate_gemm(
    const float* __restrict__ facts, const float* __restrict__ q,
    const float* __restrict__ pm, const bf16* __restrict__ Wz1b,
    const float* __restrict__ bz1, const float* __restrict__ wz2,
    float* __restrict__ score)
{
  constexpr int TS = 80;
  __shared__ bf16 As[128*TS];
  __shared__ bf16 Bs[128*TS];
  __shared__ float qs[1024];
  __shared__ float ms[1024];
  int tid = threadIdx.x;
  int b  = blockIdx.y;
  int n0 = blockIdx.x * 128;
  int w = tid >> 6, lane = tid & 63;
  int wm = w >> 1, wn = w & 1;
  int quad = lane >> 4, col = lane & 15;

  for (int i = tid; i < 1024; i += 256){ qs[i] = q[b*1024 + i]; ms[i] = pm[b*1024 + i]; }
  __syncthreads();

  floatx4 acc[4][4];
  #pragma unroll
  for (int a = 0; a < 4; ++a)
    #pragma unroll
    for (int c = 0; c < 4; ++c) acc[a][c] = (floatx4){0.f,0.f,0.f,0.f};

  for (int it = 0; it < 64; ++it){
    int k0 = it * 64;
    int qd = k0 >> 10;
    int kk0 = k0 & 1023;
    #pragma unroll
    for (int i = 0; i < 4; ++i){
      int c = tid + i*256;
      int r = c >> 3, cc = c & 7;
      int kk = kk0 + cc*8;
      const float* fp = facts + (size_t)(b*128 + r)*1024 + kk;
      float f[8], aux[8];
      *(float4*)(f)   = *(const float4*)(fp);
      *(float4*)(f+4) = *(const float4*)(fp + 4);
      const float* av = (qd == 0 || qd == 2) ? qs : ms;
      *(float4*)(aux)   = *(const float4*)(av + kk);
      *(float4*)(aux+4) = *(const float4*)(av + kk + 4);
      union { bf16 h[8]; short8 s8; } u;
      if (qd < 2){
        #pragma unroll
        for (int j = 0; j < 8; ++j) u.h[j] = __float2bfloat16(f[j]*aux[j]);
      } else {
        #pragma unroll
        for (int j = 0; j < 8; ++j) u.h[j] = __float2bfloat16(fabsf(f[j]-aux[j]));
      }
      *(short8*)&As[r*TS + cc*8] = u.s8;
    }
    #pragma unroll
    for (int i = 0; i < 4; ++i){
      int c = tid + i*256;
      int r = c >> 3, cc = c & 7;
      *(uint4v*)&Bs[r*TS + cc*8] = *(const uint4v*)(Wz1b + (size_t)(n0 + r)*4096 + k0 + cc*8);
    }
    __syncthreads();
    #pragma unroll
    for (int kt = 0; kt < 2; ++kt){
      short8 af[4], bfv[4];
      #pragma unroll
      for (int mt = 0; mt < 4; ++mt)
        af[mt] = *(const short8*)&As[(wm*64 + mt*16 + col)*TS + kt*32 + quad*8];
      #pragma unroll
      for (int nt = 0; nt < 4; ++nt)
        bfv[nt] = *(const short8*)&Bs[(wn*64 + nt*16 + col)*TS + kt*32 + quad*8];
      #pragma unroll
      for (int mt = 0; mt < 4; ++mt)
        #pragma unroll
        for (int nt = 0; nt < 4; ++nt)
          acc[mt][nt] = __builtin_amdgcn_mfma_f32_16x16x32_bf16(af[mt], bfv[nt], acc[mt][nt], 0,0,0);
    }
    __syncthreads();
  }
  #pragma unroll
  for (int mt = 0; mt < 4; ++mt){
    float part[4] = {0.f,0.f,0.f,0.f};
    #pragma unroll
    for (int nt = 0; nt < 4; ++nt){
      int n = n0 + wn*64 + nt*16 + col;
      float b1 = bz1[n], w2 = wz2[n];
      #pragma unroll
      for (int rr = 0; rr < 4; ++rr)
        part[rr] += tanh_f(acc[mt][nt][rr] + b1) * w2;
    }
    #pragma unroll
    for (int rr = 0; rr < 4; ++rr){
      float p = part[rr];
      p += __shfl_xor(p, 1); p += __shfl_xor(p, 2);
      p += __shfl_xor(p, 4); p += __shfl_xor(p, 8);
      if (col == 0)
        atomicAdd(&score[b*128 + wm*64 + mt*16 + quad*4 + rr], p);
    }
  }
}

// ---------------- generic 128x128 bf16 GEMM (B^T layout, R2-proven form) ----------------
template<int MODE>
__global__ __launch_bounds__(256, 2) void gemm_bt(
    const bf16* __restrict__ A, const bf16* __restrict__ Bm, int K,
    bf16* __restrict__ Pout, const float* __restrict__ bias, float* __restrict__ out)
{
  constexpr int TS = 80;
  __shared__ bf16 As[128*TS];
  __shared__ bf16 Bs[128*TS];
  int tid = threadIdx.x;
  int m0 = blockIdx.y * 128, n0 = blockIdx.x * 128;
  int w = tid >> 6, lane = tid & 63;
  int wm = w >> 1, wn = w & 1;
  int quad = lane >> 4, col = lane & 15;

  floatx4 acc[4][4];
  #pragma unroll
  for (int a = 0; a < 4; ++a)
    #pragma unroll
    for (int c = 0; c < 4; ++c) acc[a][c] = (floatx4){0.f,0.f,0.f,0.f};

  int nkb = K >> 6;
  for (int it = 0; it < nkb; ++it){
    int k0 = it * 64;
    #pragma unroll
    for (int i = 0; i < 4; ++i){
      int c = tid + i*256;
      int r = c >> 3, cc = c & 7;
      *(uint4v*)&As[r*TS + cc*8] = *(const uint4v*)(A  + (size_t)(m0 + r)*K + k0 + cc*8);
      *(uint4v*)&Bs[r*TS + cc*8] = *(const uint4v*)(Bm + (size_t)(n0 + r)*K + k0 + cc*8);
    }
    __syncthreads();
    #pragma unroll
    for (int kt = 0; kt < 2; ++kt){
      short8 af[4], bfv[4];
      #pragma unroll
      for (int mt = 0; mt < 4; ++mt)
        af[mt] = *(const short8*)&As[(wm*64 + mt*16 + col)*TS + kt*32 + quad*8];
      #pragma unroll
      for (int nt = 0; nt < 4; ++nt)
        bfv[nt] = *(const short8*)&Bs[(wn*64 + nt*16 + col)*TS + kt*32 + quad*8];
      #pragma unroll
      for (int mt = 0; mt < 4; ++mt)
        #pragma unroll
        for (int nt = 0; nt < 4; ++nt)
          acc[mt][nt] = __builtin_amdgcn_mfma_f32_16x16x32_bf16(af[mt], bfv[nt], acc[mt][nt], 0,0,0);
    }
    __syncthreads();
  }
  #pragma unroll
  for (int mt = 0; mt < 4; ++mt)
    #pragma unroll
    for (int nt = 0; nt < 4; ++nt)
      #pragma unroll
      for (int rr = 0; rr < 4; ++rr){
        int m = m0 + wm*64 + mt*16 + quad*4 + rr;
        int n = n0 + wn*64 + nt*16 + col;
        float v = acc[mt][nt][rr];
        if (MODE == 0){
          Pout[((size_t)(m & 127)*128 + (m >> 7))*2048 + n] = __float2bfloat16(v);
        } else {
          out[(size_t)m*1024 + n] = fmaxf(v + bias[n], 0.f);
        }
      }
}

// ---------------- the sequential scan ----------------
// 256 blocks; group g = blockIdx&7 (XCD-affine under measured round-robin
// dispatch), col block nb = blockIdx>>3. One-time runtime XCD discovery
// (s_getreg XCC_ID builtin + agent-atomic exchange) picks the coherence tier:
// all-same-XCD group -> fast (plain store / sc0 load, XCD-L2 coherent);
// otherwise -> slow (sc0 sc1, R6-proven). Protocol itself is R6's passing
// epoch-tagged data-poll in both tiers (correct under ANY mapping).
__global__ __launch_bounds__(256, 1) void scan_kernel(
    const bf16* __restrict__ UrU, const bf16* __restrict__ P,
    const float* __restrict__ G, const float* __restrict__ bias_r,
    const float* __restrict__ bw, const float* __restrict__ bu,
    unsigned long long* __restrict__ Cpub, float* __restrict__ Cfinal,
    unsigned int* __restrict__ xcc_slots)
{
  constexpr int CS = 1040;               // padded LDS stride (bf16), 16B-aligned
  __shared__ bf16 Cs[16*CS];
  __shared__ float Qex[2*16*32];         // [matrix][batch][col]
  int tid = threadIdx.x;
  int g  = blockIdx.x & 7;               // XCD-affine batch group 0..7
  int nb = blockIdx.x >> 3;              // column block 0..31
  int b0 = g * 16, j0 = nb * 32;
  int w = tid >> 6, lane = tid & 63;
  int quad = lane >> 4, col = lane & 15;

  // ---- one-time XCD discovery; all blocks co-resident (scan requires it) ----
  // hwreg encoding: id=20 (HW_REG_XCC_ID, measured m09), offset=0, size=32.
  unsigned int my_tag = __builtin_amdgcn_s_getreg(20 | (31u << 11)) + 1u;
  bool fast;
  {
    unsigned int* xs = xcc_slots + g*32;
    if (tid == 0)
      __hip_atomic_store(&xs[nb], my_tag, __ATOMIC_RELAXED, __HIP_MEMORY_SCOPE_AGENT);
    unsigned long long bad;
    for (;;){
      unsigned int v = (lane < 32)
        ? __hip_atomic_load(&xs[lane], __ATOMIC_RELAXED, __HIP_MEMORY_SCOPE_AGENT)
        : my_tag;
      if (__ballot(v == 0u) == 0ull){ bad = __ballot(v != my_tag); break; }
      __builtin_amdgcn_s_sleep(1);
    }
    fast = (bad == 0ull);                // wave-uniform by construction
  }

  // B-fragments in registers: wave w -> matrix (w>>1), n-half (w&1)
  short8 bfrag[32];
  {
    int n = ((w >> 1) << 10) + j0 + ((w & 1) << 4) + col;
    const bf16* src = UrU + (size_t)n*1024 + (quad << 3);
    #pragma unroll
    for (int kt = 0; kt < 32; ++kt) bfrag[kt] = *(const short8*)(src + kt*32);
  }

  int r  = tid >> 4;                     // batch row 0..15
  int jp = (tid & 15) * 2;               // col pair
  float c0 = 0.f, c1 = 0.f;
  float2 brv = *(const float2*)(bias_r + j0 + jp);
  float2 bwv = *(const float2*)(bw     + j0 + jp);
  float2 buv = *(const float2*)(bu     + j0 + jp);

  for (int s = 0; s < 128; ++s){
    // prefetch P/G for this step (independent of the handshake)
    const bf16* Ps = P + (size_t)s*(128*2048) + (size_t)(b0 + r)*2048 + j0 + jp;
    unsigned int up1 = *(const unsigned int*)Ps;
    unsigned int up2 = *(const unsigned int*)(Ps + 1024);
    float gg = G[(b0 + r)*128 + s];

    // poll-the-data: this group's C = 16 x 512 tagged u64 = 4096 dwordx4.
    // Accept when every high word carries epoch s; detection returns the data.
    const uint4v* Cg = (const uint4v*)
      (Cpub + (size_t)(s & 1)*65536 + (size_t)b0*512);
    uint4v vv[16];
    unsigned int expct = (unsigned int)s;
    for (;;){
      if (fast){
        #pragma unroll
        for (int i = 0; i < 16; ++i) vv[i] = ld_l2_u128(Cg + tid + i*256);
      } else {
        #pragma unroll
        for (int i = 0; i < 16; ++i) vv[i] = ld_cg_u128(Cg + tid + i*256);
      }
      waitcnt_vm0();
      unsigned int bad = 0;
      #pragma unroll
      for (int i = 0; i < 16; ++i)
        bad |= (vv[i].y ^ expct) | (vv[i].w ^ expct);
      if (__ballot(bad != 0u) == 0ull) break;
      __builtin_amdgcn_s_sleep(1);
    }
    #pragma unroll
    for (int i = 0; i < 16; ++i){
      int p = tid + i*256;               // pair-of-u64 index 0..4095
      int rr = p >> 8, pi = p & 255;     // 256 pairs per batch row
      unsigned long long wdat = (unsigned long long)vv[i].x
                              | ((unsigned long long)vv[i].z << 32);
      *(unsigned long long*)&Cs[rr*CS + pi*4] = wdat;   // 4 bf16 cols
    }
    __syncthreads();                     // barrier #1: Cs ready

    // Q = C @ [Ur;U]^T (this block's 32 cols), two independent MFMA chains
    floatx4 a0 = (floatx4){0.f,0.f,0.f,0.f}, a1 = (floatx4){0.f,0.f,0.f,0.f};
    {
      const bf16* Ap = Cs + col*CS + (quad << 3);
      #pragma unroll
      for (int kt = 0; kt < 16; ++kt){
        short8 a = *(const short8*)(Ap + kt*32);
        a0 = __builtin_amdgcn_mfma_f32_16x16x32_bf16(a, bfrag[kt], a0, 0,0,0);
      }
      #pragma unroll
      for (int kt = 16; kt < 32; ++kt){
        short8 a = *(const short8*)(Ap + kt*32);
        a1 = __builtin_amdgcn_mfma_f32_16x16x32_bf16(a, bfrag[kt], a1, 0,0,0);
      }
    }
    {
      int mi = w >> 1, nh = w & 1;
      #pragma unroll
      for (int rr = 0; rr < 4; ++rr)
        Qex[mi*512 + (quad*4 + rr)*32 + nh*16 + col] = a0[rr] + a1[rr];
    }
    __syncthreads();                     // barrier #2: Qex ready

    // elementwise GRU-style update: thread owns (batch r, cols jp,jp+1)
    float p1a = __bfloat162float(*(const bf16*)&up1);
    float p1b = __bfloat162float(*((const bf16*)&up1 + 1));
    float p2a = __bfloat162float(*(const bf16*)&up2);
    float p2b = __bfloat162float(*((const bf16*)&up2 + 1));
    float2 q1 = *(const float2*)&Qex[r*32 + jp];
    float2 q2 = *(const float2*)&Qex[512 + r*32 + jp];
    float ra = sigm_f(p1a + q1.x + brv.x);
    float ha = tanh_f(p2a + bwv.x + ra*(q2.x + buv.x));
    c0 = gg*ha + (1.f - gg)*c0;
    float rb = sigm_f(p1b + q1.y + brv.y);
    float hb = tanh_f(p2b + bwv.y + rb*(q2.y + buv.y));
    c1 = gg*hb + (1.f - gg)*c1;

    // publish tagged {epoch=s+1, c0,c1}; no ack, no flag, no extra barrier.
    if (s != 127){
      union { bf16 h[2]; unsigned int u; } pk;
      pk.h[0] = __float2bfloat16(c0);
      pk.h[1] = __float2bfloat16(c1);
      unsigned long long wd = ((unsigned long long)(unsigned int)(s + 1) << 32)
                            | (unsigned long long)pk.u;
      unsigned long long* dst = Cpub + (size_t)((s & 1) ^ 1)*65536
                              + (size_t)(b0 + r)*512 + ((j0 + jp) >> 1);
      if (fast) st_l2_u64(dst, wd); else st_cg_u64(dst, wd);
    }
  }
  *(float2*)&Cfinal[(size_t)(b0 + r)*1024 + j0 + jp] = make_float2(c0, c1);
}

// ---------------- host launch ----------------
extern "C" void kernel_launch(void* const* d_in, const int* in_sizes, int n_in,
                              void* d_out, int out_size, void* d_ws, size_t ws_size,
                              hipStream_t stream) {
  const float* facts     = (const float*)d_in[0];
  const float* questions = (const float*)d_in[1];
  const float* prevM     = (const float*)d_in[2];
  const float* Wr        = (const float*)d_in[3];
  const float* br        = (const float*)d_in[4];
  const float* Ur        = (const float*)d_in[5];
  const float* bur       = (const float*)d_in[6];
  const float* Wf        = (const float*)d_in[7];
  const float* bw        = (const float*)d_in[8];
  const float* U         = (const float*)d_in[9];
  const float* bu        = (const float*)d_in[10];
  const float* Wz1       = (const float*)d_in[11];
  const float* bz1       = (const float*)d_in[12];
  const float* Wz2       = (const float*)d_in[13];
  const float* Wm        = (const float*)d_in[15];
  const float* bm        = (const float*)d_in[16];
  float* out = (float*)d_out;

  char* ws = (char*)d_ws;
  float*              score   = (float*)(ws + OFF_SCORE);
  unsigned int*       xccs    = (unsigned int*)(ws + OFF_XCC);
  unsigned long long* Cpub    = (unsigned long long*)(ws + OFF_CPUB);
  float*              G       = (float*)(ws + OFF_G);
  float*              bias_r  = (float*)(ws + OFF_BIASR);
  float*              Cfin    = (float*)(ws + OFF_CFIN);
  bf16*               concat  = (bf16*)(ws + OFF_CONCAT);
  bf16*               facts_b = (bf16*)(ws + OFF_FACTS);
  bf16*               Wz1_b   = (bf16*)(ws + OFF_WZ1);
  bf16*               WrW_b   = (bf16*)(ws + OFF_WRW);
  bf16*               UrU_b   = (bf16*)(ws + OFF_URU);
  bf16*               Wm_b    = (bf16*)(ws + OFF_WM);
  bf16*               P       = (bf16*)(ws + OFF_P);

  hipMemsetAsync(ws, 0, ZERO_BYTES, stream);   // score + xcc slots + Cpub buf0

  cast_f32_bf16<<<16384, 256, 0, stream>>>(facts, facts_b, 16777216);
  cast_f32_bf16<<< 4096, 256, 0, stream>>>(Wz1, Wz1_b, 4194304);
  cast_f32_bf16<<< 1024, 256, 0, stream>>>(Wr, WrW_b,           1048576);
  cast_f32_bf16<<< 1024, 256, 0, stream>>>(Wf, WrW_b + 1048576, 1048576);
  cast_f32_bf16<<< 1024, 256, 0, stream>>>(Ur, UrU_b,           1048576);
  cast_f32_bf16<<< 1024, 256, 0, stream>>>(U,  UrU_b + 1048576, 1048576);
  cast_f32_bf16<<< 3072, 256, 0, stream>>>(Wm, Wm_b, 3145728);
  add_bias_k<<<4, 256, 0, stream>>>(br, bur, bias_r);

  gate_gemm<<<dim3(8, 128), 256, 0, stream>>>(facts, questions, prevM, Wz1_b, bz1, Wz2, score);
  softmax128<<<128, 128, 0, stream>>>(score, G);

  gemm_bt<0><<<dim3(16, 128), 256, 0, stream>>>(facts_b, WrW_b, 1024, P, nullptr, nullptr);

  scan_kernel<<<256, 256, 0, stream>>>(UrU_b, P, G, bias_r, bw, bu, Cpub, Cfin, xccs);

  build_concat<<<384, 256, 0, stream>>>(prevM, Cfin, questions, concat);
  gemm_bt<1><<<dim3(8, 1), 256, 0, stream>>>(concat, Wm_b, 3072, nullptr, bm, out);
}